// Round 1
// baseline (1023.155 us; speedup 1.0000x reference)
//
#include <hip/hip_runtime.h>
#include <hip/hip_bf16.h>
#include <cstdint>

#define BN_EPS 1e-5f

// ============================ edge preprocessing ============================

// Detect whether the edge buffer is int64 (JAX x64 on) or int32 (canonicalized).
// For int64 with values < 2^31, every odd 32-bit word (high half) is 0.
// For int32 random indices, odd words are nonzero with overwhelming probability.
// Reads only the first 2E words, which is safe for both layouts.
__global__ __launch_bounds__(256) void detect_k(const unsigned* __restrict__ eb,
                                                int E, int* __restrict__ flag) {
  int nz = 0;
  for (long long i = (long long)blockIdx.x * 256 + threadIdx.x; i < E;
       i += (long long)gridDim.x * 256)
    nz |= (eb[2 * i + 1] != 0u);
  if (__any(nz) && (threadIdx.x & 63) == 0) atomicOr(flag, 1);
}

__device__ __forceinline__ void load_edge(const void* eb, int E, bool w64,
                                          int e, int& s, int& d) {
  if (w64) {
    const long long* p = (const long long*)eb;
    s = (int)p[e];
    d = (int)p[E + e];
  } else {
    const int* p = (const int*)eb;
    s = p[e];
    d = p[E + e];
  }
}

__global__ __launch_bounds__(256) void count_k(const void* __restrict__ eb, int E,
                                               const int* __restrict__ flag,
                                               int* __restrict__ counts) {
  bool w64 = (*flag == 0);
  for (int e = blockIdx.x * 256 + threadIdx.x; e < E; e += gridDim.x * 256) {
    int s, d;
    load_edge(eb, E, w64, e, s, d);
    atomicAdd(&counts[d], 1);
  }
}

__global__ __launch_bounds__(256) void dinv_k(const int* __restrict__ counts,
                                              float* __restrict__ dinv, int n) {
  int i = blockIdx.x * 256 + threadIdx.x;
  if (i < n) dinv[i] = rsqrtf((float)(counts[i] + 1));  // +1 self-loop
}

// --- exclusive scan of counts -> row_ptr (3 kernels, deterministic) ---
__global__ __launch_bounds__(256) void scan1_k(const int* __restrict__ counts,
                                               int* __restrict__ bsum, int n) {
  __shared__ int ls[256];
  int t = threadIdx.x;
  int i = blockIdx.x * 256 + t;
  ls[t] = (i < n) ? counts[i] : 0;
  __syncthreads();
  for (int off = 128; off > 0; off >>= 1) {
    if (t < off) ls[t] += ls[t + off];
    __syncthreads();
  }
  if (t == 0) bsum[blockIdx.x] = ls[0];
}

__global__ __launch_bounds__(512) void scan2_k(const int* __restrict__ bsum,
                                               int* __restrict__ boff, int NB) {
  __shared__ int sa[512], sb[512];
  int t = threadIdx.x;
  int v = (t < NB) ? bsum[t] : 0;
  sa[t] = v;
  __syncthreads();
  int* src = sa;
  int* dst = sb;
  for (int off = 1; off < 512; off <<= 1) {
    int val = src[t] + (t >= off ? src[t - off] : 0);
    dst[t] = val;
    __syncthreads();
    int* tmp = src; src = dst; dst = tmp;
  }
  if (t < NB) boff[t] = src[t] - v;  // exclusive
}

__global__ __launch_bounds__(256) void scan3_k(const int* __restrict__ counts,
                                               const int* __restrict__ boff,
                                               int* __restrict__ rp, int n, int E) {
  __shared__ int sa[256], sb[256];
  int t = threadIdx.x;
  int i = blockIdx.x * 256 + t;
  int v = (i < n) ? counts[i] : 0;
  sa[t] = v;
  __syncthreads();
  int* src = sa;
  int* dst = sb;
  for (int off = 1; off < 256; off <<= 1) {
    int val = src[t] + (t >= off ? src[t - off] : 0);
    dst[t] = val;
    __syncthreads();
    int* tmp = src; src = dst; dst = tmp;
  }
  int incl = src[t];
  int off0 = boff[blockIdx.x];
  if (i < n) rp[i] = off0 + incl - v;
  if (i == n - 1) rp[n] = E;
}

__global__ __launch_bounds__(256) void fill_k(const void* __restrict__ eb, int E,
                                              const int* __restrict__ flag,
                                              const int* __restrict__ rp,
                                              int* __restrict__ cursor,
                                              const float* __restrict__ dinv,
                                              int* __restrict__ csr_src,
                                              float* __restrict__ csr_norm) {
  bool w64 = (*flag == 0);
  for (int e = blockIdx.x * 256 + threadIdx.x; e < E; e += gridDim.x * 256) {
    int s, d;
    load_edge(eb, E, w64, e, s, d);
    int pos = atomicAdd(&cursor[d], 1);
    int idx = rp[d] + pos;
    csr_src[idx] = s;
    csr_norm[idx] = dinv[s] * dinv[d];
  }
}

// ============================ GEMM (fp32, tall-skinny) ============================
// H[n][NC] = act(X)[n][128] @ W[128][NC], act = BN-scale/shift + ReLU if BN.
// 128-row x TN-col tile per block, 256 threads, 8 x (TN/16) micro-tile, BK=16.
template <int TN, int NC, bool BN>
__global__ __launch_bounds__(256) void gemm_bn(const float* __restrict__ X,
                                               const float* __restrict__ Wm,
                                               const float* __restrict__ ab,
                                               float* __restrict__ H, int n) {
  constexpr int K = 128, TM = 128, BK = 16;
  constexpr int CPT = TN / 16;  // cols per thread
  __shared__ float Xs[BK][TM + 4];
  __shared__ float Ws[BK][TN + 4];
  __shared__ float bn_s[K], bn_h[K];
  const int t = threadIdx.x;
  if (BN) {
    if (t < K) { bn_s[t] = ab[t]; bn_h[t] = ab[K + t]; }
  }
  const int m0 = blockIdx.x * TM;
  const int tr = t >> 4;   // 0..15  -> 8 rows each
  const int tc = t & 15;   // 0..15  -> CPT cols each
  float acc[8][CPT];
#pragma unroll
  for (int i = 0; i < 8; i++)
#pragma unroll
    for (int j = 0; j < CPT; j++) acc[i][j] = 0.f;

  for (int kb = 0; kb < K; kb += BK) {
    __syncthreads();  // protect LDS (and bn_s/bn_h on first iter)
    // stage X tile: 128 rows x 16 k
#pragma unroll
    for (int p = 0; p < 2; p++) {
      int row = p * 64 + (t >> 2);
      int kk = (t & 3) * 4;
      int node = m0 + row;
      float4 v = make_float4(0.f, 0.f, 0.f, 0.f);
      if (node < n) v = *(const float4*)&X[(size_t)node * K + kb + kk];
      if (BN) {
        v.x = fmaxf(fmaf(v.x, bn_s[kb + kk + 0], bn_h[kb + kk + 0]), 0.f);
        v.y = fmaxf(fmaf(v.y, bn_s[kb + kk + 1], bn_h[kb + kk + 1]), 0.f);
        v.z = fmaxf(fmaf(v.z, bn_s[kb + kk + 2], bn_h[kb + kk + 2]), 0.f);
        v.w = fmaxf(fmaf(v.w, bn_s[kb + kk + 3], bn_h[kb + kk + 3]), 0.f);
      }
      Xs[kk + 0][row] = v.x;
      Xs[kk + 1][row] = v.y;
      Xs[kk + 2][row] = v.z;
      Xs[kk + 3][row] = v.w;
    }
    // stage W tile: 16 k x TN cols
    if (TN == 128) {
#pragma unroll
      for (int p = 0; p < 2; p++) {
        int krow = p * 8 + (t >> 5);
        int c = (t & 31) * 4;
        float4 w = *(const float4*)&Wm[(size_t)(kb + krow) * NC + c];
        Ws[krow][c + 0] = w.x;
        Ws[krow][c + 1] = w.y;
        Ws[krow][c + 2] = w.z;
        Ws[krow][c + 3] = w.w;
      }
    } else {
      int krow = t >> 4;        // 0..15
      int c = (t & 15) * 4;     // 0..60
#pragma unroll
      for (int j = 0; j < 4; j++)
        Ws[krow][c + j] = (c + j < NC) ? Wm[(size_t)(kb + krow) * NC + c + j] : 0.f;
    }
    __syncthreads();
#pragma unroll
    for (int kk = 0; kk < BK; kk++) {
      float a_[8], b_[CPT];
#pragma unroll
      for (int i = 0; i < 8; i++) a_[i] = Xs[kk][tr * 8 + i];
#pragma unroll
      for (int j = 0; j < CPT; j++) b_[j] = Ws[kk][tc * CPT + j];
#pragma unroll
      for (int i = 0; i < 8; i++)
#pragma unroll
        for (int j = 0; j < CPT; j++) acc[i][j] = fmaf(a_[i], b_[j], acc[i][j]);
    }
  }
  // store
#pragma unroll
  for (int i = 0; i < 8; i++) {
    int node = m0 + tr * 8 + i;
    if (node >= n) continue;
    if (NC == 128) {
      float4 v0 = make_float4(acc[i][0], acc[i][1], acc[i][2], acc[i][3]);
      float4 v1 = make_float4(acc[i][CPT - 4], acc[i][CPT - 3], acc[i][CPT - 2],
                              acc[i][CPT - 1]);
      *(float4*)&H[(size_t)node * NC + tc * CPT] = v0;
      *(float4*)&H[(size_t)node * NC + tc * CPT + 4] = v1;
    } else {
#pragma unroll
      for (int j = 0; j < CPT; j++) {
        int c = tc * CPT + j;
        if (c < NC) H[(size_t)node * NC + c] = acc[i][j];
      }
    }
  }
}

// ============================ aggregation (gather) ============================
// out[i][:] = bias + dinv[i]^2 * H[i][:] + sum_{e in CSR[i]} norm[e] * H[src[e]][:]
__global__ __launch_bounds__(256) void agg128(const float* __restrict__ H,
                                              const int* __restrict__ rp,
                                              const int* __restrict__ csr_src,
                                              const float* __restrict__ csr_norm,
                                              const float* __restrict__ dinv,
                                              const float* __restrict__ bias,
                                              float* __restrict__ out, int n) {
  int wid = threadIdx.x >> 6, lane = threadIdx.x & 63;
  int i = blockIdx.x * 4 + wid;
  if (i >= n) return;
  float2 acc = *(const float2*)&bias[lane * 2];
  float di = dinv[i];
  float2 hv = *(const float2*)&H[(size_t)i * 128 + lane * 2];
  float dii = di * di;
  acc.x = fmaf(hv.x, dii, acc.x);
  acc.y = fmaf(hv.y, dii, acc.y);
  int e1 = rp[i + 1];
  for (int e = rp[i]; e < e1; e++) {
    int s = csr_src[e];
    float w = csr_norm[e];
    float2 v = *(const float2*)&H[(size_t)s * 128 + lane * 2];
    acc.x = fmaf(v.x, w, acc.x);
    acc.y = fmaf(v.y, w, acc.y);
  }
  *(float2*)&out[(size_t)i * 128 + lane * 2] = acc;
}

__global__ __launch_bounds__(256) void agg40(const float* __restrict__ H,
                                             const int* __restrict__ rp,
                                             const int* __restrict__ csr_src,
                                             const float* __restrict__ csr_norm,
                                             const float* __restrict__ dinv,
                                             const float* __restrict__ bias,
                                             float* __restrict__ out, int n) {
  int wid = threadIdx.x >> 6, lane = threadIdx.x & 63;
  int i = blockIdx.x * 4 + wid;
  if (i >= n || lane >= 40) return;
  float di = dinv[i];
  float acc = fmaf(H[(size_t)i * 40 + lane], di * di, bias[lane]);
  int e1 = rp[i + 1];
  for (int e = rp[i]; e < e1; e++) {
    int s = csr_src[e];
    float w = csr_norm[e];
    acc = fmaf(H[(size_t)s * 40 + lane], w, acc);
  }
  out[(size_t)i * 40 + lane] = acc;
}

// ============================ batchnorm stats ============================
__global__ __launch_bounds__(256) void bn_stats(const float* __restrict__ H, int n,
                                                float* __restrict__ acc) {
  int t = threadIdx.x;
  int c = t & 127;
  int half = t >> 7;
  float s = 0.f, s2 = 0.f;
  for (int r = blockIdx.x * 2 + half; r < n; r += gridDim.x * 2) {
    float v = H[(size_t)r * 128 + c];
    s += v;
    s2 = fmaf(v, v, s2);
  }
  __shared__ float ls[256], ls2[256];
  ls[t] = s;
  ls2[t] = s2;
  __syncthreads();
  if (half == 0) {
    s = ls[c] + ls[128 + c];
    s2 = ls2[c] + ls2[128 + c];
    atomicAdd(&acc[c], s);
    atomicAdd(&acc[128 + c], s2);
  }
}

__global__ void bn_final(const float* __restrict__ acc, const float* __restrict__ g,
                         const float* __restrict__ bt, int n,
                         float* __restrict__ ab) {
  int c = threadIdx.x;  // 128 threads
  float inv_n = 1.0f / (float)n;
  float mean = acc[c] * inv_n;
  float var = acc[128 + c] * inv_n - mean * mean;
  float sc = g[c] * rsqrtf(var + BN_EPS);
  ab[c] = sc;
  ab[128 + c] = fmaf(-mean, sc, bt[c]);
}

// ============================ launch ============================
extern "C" void kernel_launch(void* const* d_in, const int* in_sizes, int n_in,
                              void* d_out, int out_size, void* d_ws, size_t ws_size,
                              hipStream_t stream) {
  const float* x = (const float*)d_in[0];
  const void* eb = d_in[1];
  const float* W1 = (const float*)d_in[2];
  const float* b1 = (const float*)d_in[3];
  const float* g1 = (const float*)d_in[4];
  const float* bt1 = (const float*)d_in[5];
  const float* W2 = (const float*)d_in[6];
  const float* b2 = (const float*)d_in[7];
  const float* g2 = (const float*)d_in[8];
  const float* bt2 = (const float*)d_in[9];
  const float* W3 = (const float*)d_in[10];
  const float* b3 = (const float*)d_in[11];

  const int n = in_sizes[0] / 128;
  const int E = in_sizes[1] / 2;

  char* w = (char*)d_ws;
  auto alloc = [&](size_t bytes) {
    void* p = (void*)w;
    w += (bytes + 255) & ~(size_t)255;
    return p;
  };
  float* hA = (float*)alloc((size_t)n * 128 * 4);
  float* hB = (float*)alloc((size_t)n * 128 * 4);
  int* csr_src = (int*)alloc((size_t)E * 4);
  float* csr_norm = (float*)alloc((size_t)E * 4);
  float* dinv = (float*)alloc((size_t)n * 4);
  int* rp = (int*)alloc((size_t)(n + 1) * 4);
  int* bsum = (int*)alloc(512 * 4);
  int* boff = (int*)alloc(512 * 4);
  float* ab1 = (float*)alloc(256 * 4);
  float* ab2 = (float*)alloc(256 * 4);
  // contiguous zero region:
  int* counts = (int*)alloc((size_t)n * 4);
  int* cursor = (int*)alloc((size_t)n * 4);
  float* bn_acc1 = (float*)alloc(256 * 4);
  float* bn_acc2 = (float*)alloc(256 * 4);
  int* flag = (int*)alloc(256);
  size_t zbytes = (char*)flag + 256 - (char*)counts;
  hipMemsetAsync(counts, 0, zbytes, stream);

  const int NB = (n + 255) / 256;

  detect_k<<<1024, 256, 0, stream>>>((const unsigned*)eb, E, flag);
  count_k<<<2048, 256, 0, stream>>>(eb, E, flag, counts);
  dinv_k<<<NB, 256, 0, stream>>>(counts, dinv, n);
  scan1_k<<<NB, 256, 0, stream>>>(counts, bsum, n);
  scan2_k<<<1, 512, 0, stream>>>(bsum, boff, NB);
  scan3_k<<<NB, 256, 0, stream>>>(counts, boff, rp, n, E);
  fill_k<<<2048, 256, 0, stream>>>(eb, E, flag, rp, cursor, dinv, csr_src, csr_norm);

  const int GB = (n + 127) / 128;   // gemm blocks
  const int AB = (n + 3) / 4;       // agg blocks

  // layer 1
  gemm_bn<128, 128, false><<<GB, 256, 0, stream>>>(x, W1, nullptr, hA, n);
  agg128<<<AB, 256, 0, stream>>>(hA, rp, csr_src, csr_norm, dinv, b1, hB, n);
  bn_stats<<<1024, 256, 0, stream>>>(hB, n, bn_acc1);
  bn_final<<<1, 128, 0, stream>>>(bn_acc1, g1, bt1, n, ab1);
  // layer 2 (BN+ReLU fused into GEMM input load)
  gemm_bn<128, 128, true><<<GB, 256, 0, stream>>>(hB, W2, ab1, hA, n);
  agg128<<<AB, 256, 0, stream>>>(hA, rp, csr_src, csr_norm, dinv, b2, hB, n);
  bn_stats<<<1024, 256, 0, stream>>>(hB, n, bn_acc2);
  bn_final<<<1, 128, 0, stream>>>(bn_acc2, g2, bt2, n, ab2);
  // layer 3: GEMM 128->40 then 40-channel aggregate into d_out
  gemm_bn<64, 40, true><<<GB, 256, 0, stream>>>(hB, W3, ab2, hA, n);
  agg40<<<AB, 256, 0, stream>>>(hA, rp, csr_src, csr_norm, dinv, b3, (float*)d_out, n);
}

// Round 3
// 692.610 us; speedup vs baseline: 1.4772x; 1.4772x over previous
//
#include <hip/hip_runtime.h>
#include <hip/hip_fp16.h>
#include <cstdint>

#define BN_EPS 1e-5f

typedef _Float16 f16;
typedef _Float16 f16x8 __attribute__((ext_vector_type(8)));
typedef _Float16 f16x4 __attribute__((ext_vector_type(4)));
typedef float f32x4 __attribute__((ext_vector_type(4)));

// ============================ edge preprocessing ============================

// Detect int64 vs int32 edge buffer (JAX may canonicalize int64 -> int32).
__global__ __launch_bounds__(256) void detect_k(const unsigned* __restrict__ eb,
                                                int E, int* __restrict__ flag) {
  int nz = 0;
  for (long long i = (long long)blockIdx.x * 256 + threadIdx.x; i < E;
       i += (long long)gridDim.x * 256)
    nz |= (eb[2 * i + 1] != 0u);
  if (__any(nz) && (threadIdx.x & 63) == 0) atomicOr(flag, 1);
}

__device__ __forceinline__ void load_edge(const void* eb, int E, bool w64,
                                          int e, int& s, int& d) {
  if (w64) {
    const long long* p = (const long long*)eb;
    s = (int)p[e];
    d = (int)p[E + e];
  } else {
    const int* p = (const int*)eb;
    s = p[e];
    d = p[E + e];
  }
}

__global__ __launch_bounds__(256) void count_k(const void* __restrict__ eb, int E,
                                               const int* __restrict__ flag,
                                               int* __restrict__ counts) {
  bool w64 = (*flag == 0);
  for (int e = blockIdx.x * 256 + threadIdx.x; e < E; e += gridDim.x * 256) {
    int s, d;
    load_edge(eb, E, w64, e, s, d);
    atomicAdd(&counts[d], 1);
  }
}

__global__ __launch_bounds__(256) void dinv_k(const int* __restrict__ counts,
                                              float* __restrict__ dinv, int n) {
  int i = blockIdx.x * 256 + threadIdx.x;
  if (i < n) dinv[i] = rsqrtf((float)(counts[i] + 1));  // +1 self-loop
}

// --- exclusive scan of counts -> row_ptr ---
__global__ __launch_bounds__(256) void scan1_k(const int* __restrict__ counts,
                                               int* __restrict__ bsum, int n) {
  __shared__ int ls[256];
  int t = threadIdx.x;
  int i = blockIdx.x * 256 + t;
  ls[t] = (i < n) ? counts[i] : 0;
  __syncthreads();
  for (int off = 128; off > 0; off >>= 1) {
    if (t < off) ls[t] += ls[t + off];
    __syncthreads();
  }
  if (t == 0) bsum[blockIdx.x] = ls[0];
}

__global__ __launch_bounds__(512) void scan2_k(const int* __restrict__ bsum,
                                               int* __restrict__ boff, int NB) {
  __shared__ int sa[512], sb[512];
  int t = threadIdx.x;
  int v = (t < NB) ? bsum[t] : 0;
  sa[t] = v;
  __syncthreads();
  int* src = sa;
  int* dst = sb;
  for (int off = 1; off < 512; off <<= 1) {
    int val = src[t] + (t >= off ? src[t - off] : 0);
    dst[t] = val;
    __syncthreads();
    int* tmp = src; src = dst; dst = tmp;
  }
  if (t < NB) boff[t] = src[t] - v;  // exclusive
}

__global__ __launch_bounds__(256) void scan3_k(const int* __restrict__ counts,
                                               const int* __restrict__ boff,
                                               int* __restrict__ rp, int n, int E) {
  __shared__ int sa[256], sb[256];
  int t = threadIdx.x;
  int i = blockIdx.x * 256 + t;
  int v = (i < n) ? counts[i] : 0;
  sa[t] = v;
  __syncthreads();
  int* src = sa;
  int* dst = sb;
  for (int off = 1; off < 256; off <<= 1) {
    int val = src[t] + (t >= off ? src[t - off] : 0);
    dst[t] = val;
    __syncthreads();
    int* tmp = src; src = dst; dst = tmp;
  }
  int incl = src[t];
  int off0 = boff[blockIdx.x];
  if (i < n) rp[i] = off0 + incl - v;
  if (i == n - 1) rp[n] = E;
}

// packed CSR entry: {src, norm_bits} -> single 8B store per edge
__global__ __launch_bounds__(256) void fill_k(const void* __restrict__ eb, int E,
                                              const int* __restrict__ flag,
                                              const int* __restrict__ rp,
                                              int* __restrict__ cursor,
                                              const float* __restrict__ dinv,
                                              int2* __restrict__ csr) {
  bool w64 = (*flag == 0);
  for (int e = blockIdx.x * 256 + threadIdx.x; e < E; e += gridDim.x * 256) {
    int s, d;
    load_edge(eb, E, w64, e, s, d);
    int pos = atomicAdd(&cursor[d], 1);
    int2 ent;
    ent.x = s;
    ent.y = __float_as_int(dinv[s] * dinv[d]);
    csr[rp[d] + pos] = ent;
  }
}

// ============================ W prep: transpose + fp16 ============================
// Wt[nc][k] = (f16) W[k][nc]
__global__ void prep_w(const float* __restrict__ W, f16* __restrict__ Wt, int NC) {
  int nc = blockIdx.x;
  int k = threadIdx.x;  // 128
  Wt[(size_t)nc * 128 + k] = (f16)W[(size_t)k * NC + nc];
}

// ============================ GEMM (MFMA f16) ============================
// H[n][NC] = act(X)[n][128] @ W[128][NC]; act = BN scale/shift + ReLU if BN.
// Block: 256 thr = 4 waves, tile 128 rows. Operand swap: mfma(Wfrag, Xfrag)
// puts 4 consecutive H-columns in each lane -> vectorized f16x4 stores.
template <int NCP, int NC, bool BN, bool F32IN>
__global__ __launch_bounds__(256) void gemm_mfma(const void* __restrict__ Xv,
                                                 const f16* __restrict__ Wt,
                                                 const float* __restrict__ ab,
                                                 f16* __restrict__ H, int n) {
  constexpr int CB = NCP / 16;
  __shared__ f16 Xs[128][136];
  __shared__ f16 Ws[NCP][136];
  const int t = threadIdx.x;
  const int m0 = blockIdx.x * 128;

  // ---- stage X tile (fp32 or fp16 global -> fp16 LDS, BN+ReLU fused) ----
  if constexpr (F32IN) {
    const float* X = (const float*)Xv;
#pragma unroll
    for (int p = 0; p < 16; p++) {
      int idx = p * 256 + t;          // 4096 float4 units
      int row = idx >> 5, c = (idx & 31) * 4;
      float4 v = make_float4(0.f, 0.f, 0.f, 0.f);
      if (m0 + row < n) v = *(const float4*)&X[(size_t)(m0 + row) * 128 + c];
      if (BN) {
        v.x = fmaxf(fmaf(v.x, ab[c + 0], ab[128 + c + 0]), 0.f);
        v.y = fmaxf(fmaf(v.y, ab[c + 1], ab[128 + c + 1]), 0.f);
        v.z = fmaxf(fmaf(v.z, ab[c + 2], ab[128 + c + 2]), 0.f);
        v.w = fmaxf(fmaf(v.w, ab[c + 3], ab[128 + c + 3]), 0.f);
      }
      f16x4 h = {(f16)v.x, (f16)v.y, (f16)v.z, (f16)v.w};
      *(f16x4*)&Xs[row][c] = h;
    }
  } else {
    const f16* X = (const f16*)Xv;
#pragma unroll
    for (int p = 0; p < 8; p++) {
      int idx = p * 256 + t;          // 2048 f16x8 units
      int row = idx >> 4, c = (idx & 15) * 8;
      f16x8 v = {0, 0, 0, 0, 0, 0, 0, 0};
      if (m0 + row < n) v = *(const f16x8*)&X[(size_t)(m0 + row) * 128 + c];
      if (BN) {
#pragma unroll
        for (int j = 0; j < 8; j++) {
          float f = (float)v[j];
          f = fmaxf(fmaf(f, ab[c + j], ab[128 + c + j]), 0.f);
          v[j] = (f16)f;
        }
      }
      *(f16x8*)&Xs[row][c] = v;
    }
  }
  // ---- stage W tile (fp16 global, rows >= NC zeroed) ----
#pragma unroll
  for (int idx = t; idx < NCP * 16; idx += 256) {
    int row = idx >> 4, c = (idx & 15) * 8;
    f16x8 v = {0, 0, 0, 0, 0, 0, 0, 0};
    if (row < NC) v = *(const f16x8*)&Wt[(size_t)row * 128 + c];
    *(f16x8*)&Ws[row][c] = v;
  }
  __syncthreads();

  const int w = t >> 6, l = t & 63;
  const int lr = l & 15, lq = l >> 4;
  f32x4 acc[2][CB];
#pragma unroll
  for (int i = 0; i < 2; i++)
#pragma unroll
    for (int j = 0; j < CB; j++) acc[i][j] = (f32x4){0.f, 0.f, 0.f, 0.f};

#pragma unroll
  for (int kb = 0; kb < 4; kb++) {
    f16x8 xf0 = *(const f16x8*)&Xs[w * 32 + lr][kb * 32 + lq * 8];
    f16x8 xf1 = *(const f16x8*)&Xs[w * 32 + 16 + lr][kb * 32 + lq * 8];
#pragma unroll
    for (int cb = 0; cb < CB; cb++) {
      f16x8 wf = *(const f16x8*)&Ws[cb * 16 + lr][kb * 32 + lq * 8];
      acc[0][cb] = __builtin_amdgcn_mfma_f32_16x16x32_f16(wf, xf0, acc[0][cb], 0, 0, 0);
      acc[1][cb] = __builtin_amdgcn_mfma_f32_16x16x32_f16(wf, xf1, acc[1][cb], 0, 0, 0);
    }
  }
  // ---- store: lane holds H[row = base + (l&15)][col = cb*16 + lq*4 .. +3] ----
#pragma unroll
  for (int rg = 0; rg < 2; rg++) {
    int row = m0 + w * 32 + rg * 16 + lr;
    if (row >= n) continue;
#pragma unroll
    for (int cb = 0; cb < CB; cb++) {
      int col = cb * 16 + lq * 4;
      if (NC != NCP && col >= NC) continue;
      f32x4 a = acc[rg][cb];
      f16x4 h = {(f16)a[0], (f16)a[1], (f16)a[2], (f16)a[3]};
      *(f16x4*)&H[(size_t)row * NC + col] = h;
    }
  }
}

// ============================ aggregation (gather, fp16 rows) ============================
// out[i][:] = bias + dinv[i]^2 * H[i][:] + sum_e norm[e] * H[src[e]][:]
__global__ __launch_bounds__(256) void agg128h(const f16* __restrict__ H,
                                               const int* __restrict__ rp,
                                               const int2* __restrict__ csr,
                                               const float* __restrict__ dinv,
                                               const float* __restrict__ bias,
                                               f16* __restrict__ out, int n) {
  int wid = threadIdx.x >> 6, l = threadIdx.x & 63;
  int i = blockIdx.x * 4 + wid;
  if (i >= n) return;
  float di = dinv[i];
  float2 acc = *(const float2*)&bias[l * 2];
  float2 hf = __half22float2(*(const __half2*)&H[(size_t)i * 128 + l * 2]);
  float dii = di * di;
  acc.x = fmaf(hf.x, dii, acc.x);
  acc.y = fmaf(hf.y, dii, acc.y);
  int e = rp[i], e1 = rp[i + 1];
  for (; e + 2 <= e1; e += 2) {
    int2 a = csr[e], b = csr[e + 1];
    float2 v0 = __half22float2(*(const __half2*)&H[(size_t)a.x * 128 + l * 2]);
    float2 v1 = __half22float2(*(const __half2*)&H[(size_t)b.x * 128 + l * 2]);
    float w0 = __int_as_float(a.y), w1 = __int_as_float(b.y);
    acc.x = fmaf(v0.x, w0, acc.x);
    acc.y = fmaf(v0.y, w0, acc.y);
    acc.x = fmaf(v1.x, w1, acc.x);
    acc.y = fmaf(v1.y, w1, acc.y);
  }
  if (e < e1) {
    int2 a = csr[e];
    float2 v0 = __half22float2(*(const __half2*)&H[(size_t)a.x * 128 + l * 2]);
    float w0 = __int_as_float(a.y);
    acc.x = fmaf(v0.x, w0, acc.x);
    acc.y = fmaf(v0.y, w0, acc.y);
  }
  *(__half2*)&out[(size_t)i * 128 + l * 2] = __floats2half2_rn(acc.x, acc.y);
}

__global__ __launch_bounds__(256) void agg40h(const f16* __restrict__ H,
                                              const int* __restrict__ rp,
                                              const int2* __restrict__ csr,
                                              const float* __restrict__ dinv,
                                              const float* __restrict__ bias,
                                              float* __restrict__ out, int n) {
  int wid = threadIdx.x >> 6, l = threadIdx.x & 63;
  int i = blockIdx.x * 4 + wid;
  if (i >= n || l >= 40) return;
  float di = dinv[i];
  float acc = fmaf((float)H[(size_t)i * 40 + l], di * di, bias[l]);
  int e = rp[i], e1 = rp[i + 1];
  for (; e + 2 <= e1; e += 2) {
    int2 a = csr[e], b = csr[e + 1];
    float v0 = (float)H[(size_t)a.x * 40 + l];
    float v1 = (float)H[(size_t)b.x * 40 + l];
    acc = fmaf(v0, __int_as_float(a.y), acc);
    acc = fmaf(v1, __int_as_float(b.y), acc);
  }
  if (e < e1) {
    int2 a = csr[e];
    acc = fmaf((float)H[(size_t)a.x * 40 + l], __int_as_float(a.y), acc);
  }
  out[(size_t)i * 40 + l] = acc;
}

// ============================ batchnorm stats (fp16 input) ============================
__global__ __launch_bounds__(256) void bn_stats_h(const f16* __restrict__ H, int n,
                                                  float* __restrict__ acc) {
  int t = threadIdx.x;
  int c2 = t & 63;   // half2 column
  int rg = t >> 6;   // 0..3
  float2 s = {0.f, 0.f}, s2 = {0.f, 0.f};
  for (int r = blockIdx.x * 4 + rg; r < n; r += gridDim.x * 4) {
    float2 v = __half22float2(*(const __half2*)&H[(size_t)r * 128 + c2 * 2]);
    s.x += v.x;
    s.y += v.y;
    s2.x = fmaf(v.x, v.x, s2.x);
    s2.y = fmaf(v.y, v.y, s2.y);
  }
  __shared__ float ls[4][128], ls2[4][128];
  ls[rg][c2 * 2] = s.x;
  ls[rg][c2 * 2 + 1] = s.y;
  ls2[rg][c2 * 2] = s2.x;
  ls2[rg][c2 * 2 + 1] = s2.y;
  __syncthreads();
  if (t < 128) {
    float a_ = ls[0][t] + ls[1][t] + ls[2][t] + ls[3][t];
    float b_ = ls2[0][t] + ls2[1][t] + ls2[2][t] + ls2[3][t];
    atomicAdd(&acc[t], a_);
    atomicAdd(&acc[128 + t], b_);
  }
}

__global__ void bn_final(const float* __restrict__ acc, const float* __restrict__ g,
                         const float* __restrict__ bt, int n,
                         float* __restrict__ ab) {
  int c = threadIdx.x;  // 128
  float inv_n = 1.0f / (float)n;
  float mean = acc[c] * inv_n;
  float var = acc[128 + c] * inv_n - mean * mean;
  float sc = g[c] * rsqrtf(var + BN_EPS);
  ab[c] = sc;
  ab[128 + c] = fmaf(-mean, sc, bt[c]);
}

// ============================ launch ============================
extern "C" void kernel_launch(void* const* d_in, const int* in_sizes, int n_in,
                              void* d_out, int out_size, void* d_ws, size_t ws_size,
                              hipStream_t stream) {
  const float* x = (const float*)d_in[0];
  const void* eb = d_in[1];
  const float* W1 = (const float*)d_in[2];
  const float* b1 = (const float*)d_in[3];
  const float* g1 = (const float*)d_in[4];
  const float* bt1 = (const float*)d_in[5];
  const float* W2 = (const float*)d_in[6];
  const float* b2 = (const float*)d_in[7];
  const float* g2 = (const float*)d_in[8];
  const float* bt2 = (const float*)d_in[9];
  const float* W3 = (const float*)d_in[10];
  const float* b3 = (const float*)d_in[11];

  const int n = in_sizes[0] / 128;
  const int E = in_sizes[1] / 2;

  char* w = (char*)d_ws;
  auto alloc = [&](size_t bytes) {
    void* p = (void*)w;
    w += (bytes + 255) & ~(size_t)255;
    return p;
  };
  f16* hA = (f16*)alloc((size_t)n * 128 * 2);
  f16* hB = (f16*)alloc((size_t)n * 128 * 2);
  int2* csr = (int2*)alloc((size_t)E * 8);
  float* dinv = (float*)alloc((size_t)n * 4);
  int* rp = (int*)alloc((size_t)(n + 1) * 4);
  int* bsum = (int*)alloc(512 * 4);
  int* boff = (int*)alloc(512 * 4);
  float* ab1 = (float*)alloc(256 * 4);
  float* ab2 = (float*)alloc(256 * 4);
  f16* Wt1 = (f16*)alloc(128 * 128 * 2);
  f16* Wt2 = (f16*)alloc(128 * 128 * 2);
  f16* Wt3 = (f16*)alloc(48 * 128 * 2);
  // contiguous zero region:
  int* counts = (int*)alloc((size_t)n * 4);
  int* cursor = (int*)alloc((size_t)n * 4);
  float* bn_acc1 = (float*)alloc(256 * 4);
  float* bn_acc2 = (float*)alloc(256 * 4);
  int* flag = (int*)alloc(256);
  size_t zbytes = (char*)flag + 256 - (char*)counts;
  hipMemsetAsync(counts, 0, zbytes, stream);

  const int NB = (n + 255) / 256;

  prep_w<<<128, 128, 0, stream>>>(W1, Wt1, 128);
  prep_w<<<128, 128, 0, stream>>>(W2, Wt2, 128);
  prep_w<<<40, 128, 0, stream>>>(W3, Wt3, 40);

  detect_k<<<512, 256, 0, stream>>>((const unsigned*)eb, E, flag);
  count_k<<<2048, 256, 0, stream>>>(eb, E, flag, counts);
  dinv_k<<<NB, 256, 0, stream>>>(counts, dinv, n);
  scan1_k<<<NB, 256, 0, stream>>>(counts, bsum, n);
  scan2_k<<<1, 512, 0, stream>>>(bsum, boff, NB);
  scan3_k<<<NB, 256, 0, stream>>>(counts, boff, rp, n, E);
  fill_k<<<2048, 256, 0, stream>>>(eb, E, flag, rp, cursor, dinv, csr);

  const int GB = (n + 127) / 128;  // gemm blocks
  const int AB = (n + 3) / 4;      // agg blocks

  // layer 1
  gemm_mfma<128, 128, false, true><<<GB, 256, 0, stream>>>(x, Wt1, nullptr, hA, n);
  agg128h<<<AB, 256, 0, stream>>>(hA, rp, csr, dinv, b1, hB, n);
  bn_stats_h<<<1024, 256, 0, stream>>>(hB, n, bn_acc1);
  bn_final<<<1, 128, 0, stream>>>(bn_acc1, g1, bt1, n, ab1);
  // layer 2
  gemm_mfma<128, 128, true, false><<<GB, 256, 0, stream>>>(hB, Wt2, ab1, hA, n);
  agg128h<<<AB, 256, 0, stream>>>(hA, rp, csr, dinv, b2, hB, n);
  bn_stats_h<<<1024, 256, 0, stream>>>(hB, n, bn_acc2);
  bn_final<<<1, 128, 0, stream>>>(bn_acc2, g2, bt2, n, ab2);
  // layer 3
  gemm_mfma<48, 40, true, false><<<GB, 256, 0, stream>>>(hB, Wt3, ab2, hA, n);
  agg40h<<<AB, 256, 0, stream>>>(hA, rp, csr, dinv, b3, (float*)d_out, n);
}

// Round 4
// 622.486 us; speedup vs baseline: 1.6437x; 1.1127x over previous
//
#include <hip/hip_runtime.h>
#include <hip/hip_fp16.h>
#include <cstdint>

#define BN_EPS 1e-5f

typedef _Float16 f16;
typedef _Float16 f16x8 __attribute__((ext_vector_type(8)));
typedef _Float16 f16x4 __attribute__((ext_vector_type(4)));
typedef float f32x4 __attribute__((ext_vector_type(4)));

// ============================ edge preprocessing ============================

// Detect int64 vs int32 edge buffer (JAX may canonicalize int64 -> int32).
__global__ __launch_bounds__(256) void detect_k(const unsigned* __restrict__ eb,
                                                int E, int* __restrict__ flag) {
  int nz = 0;
  for (long long i = (long long)blockIdx.x * 256 + threadIdx.x; i < E;
       i += (long long)gridDim.x * 256)
    nz |= (eb[2 * i + 1] != 0u);
  if (__any(nz) && (threadIdx.x & 63) == 0) atomicOr(flag, 1);
}

__device__ __forceinline__ void load_edge(const void* eb, int E, bool w64,
                                          int e, int& s, int& d) {
  if (w64) {
    const long long* p = (const long long*)eb;
    s = (int)p[e];
    d = (int)p[E + e];
  } else {
    const int* p = (const int*)eb;
    s = p[e];
    d = p[E + e];
  }
}

__global__ __launch_bounds__(256) void count_k(const void* __restrict__ eb, int E,
                                               const int* __restrict__ flag,
                                               int* __restrict__ counts) {
  bool w64 = (*flag == 0);
  for (int e = blockIdx.x * 256 + threadIdx.x; e < E; e += gridDim.x * 256) {
    int s, d;
    load_edge(eb, E, w64, e, s, d);
    atomicAdd(&counts[d], 1);
  }
}

// --- exclusive scan of counts -> row_ptr (dinv fused into pass 1) ---
__global__ __launch_bounds__(256) void scan1_k(const int* __restrict__ counts,
                                               int* __restrict__ bsum,
                                               float* __restrict__ dinv, int n) {
  __shared__ int ls[256];
  int t = threadIdx.x;
  int i = blockIdx.x * 256 + t;
  int c = (i < n) ? counts[i] : 0;
  if (i < n) dinv[i] = rsqrtf((float)(c + 1));  // +1 self-loop
  ls[t] = c;
  __syncthreads();
  for (int off = 128; off > 0; off >>= 1) {
    if (t < off) ls[t] += ls[t + off];
    __syncthreads();
  }
  if (t == 0) bsum[blockIdx.x] = ls[0];
}

__global__ __launch_bounds__(512) void scan2_k(const int* __restrict__ bsum,
                                               int* __restrict__ boff, int NB) {
  __shared__ int sa[512], sb[512];
  int t = threadIdx.x;
  int v = (t < NB) ? bsum[t] : 0;
  sa[t] = v;
  __syncthreads();
  int* src = sa;
  int* dst = sb;
  for (int off = 1; off < 512; off <<= 1) {
    int val = src[t] + (t >= off ? src[t - off] : 0);
    dst[t] = val;
    __syncthreads();
    int* tmp = src; src = dst; dst = tmp;
  }
  if (t < NB) boff[t] = src[t] - v;  // exclusive
}

__global__ __launch_bounds__(256) void scan3_k(const int* __restrict__ counts,
                                               const int* __restrict__ boff,
                                               int* __restrict__ rp, int n, int E) {
  __shared__ int sa[256], sb[256];
  int t = threadIdx.x;
  int i = blockIdx.x * 256 + t;
  int v = (i < n) ? counts[i] : 0;
  sa[t] = v;
  __syncthreads();
  int* src = sa;
  int* dst = sb;
  for (int off = 1; off < 256; off <<= 1) {
    int val = src[t] + (t >= off ? src[t - off] : 0);
    dst[t] = val;
    __syncthreads();
    int* tmp = src; src = dst; dst = tmp;
  }
  int incl = src[t];
  int off0 = boff[blockIdx.x];
  if (i < n) rp[i] = off0 + incl - v;
  if (i == n - 1) rp[n] = E;
}

// packed CSR entry: {src, norm_bits} -> single 8B store per edge
__global__ __launch_bounds__(256) void fill_k(const void* __restrict__ eb, int E,
                                              const int* __restrict__ flag,
                                              const int* __restrict__ rp,
                                              int* __restrict__ cursor,
                                              const float* __restrict__ dinv,
                                              int2* __restrict__ csr) {
  bool w64 = (*flag == 0);
  for (int e = blockIdx.x * 256 + threadIdx.x; e < E; e += gridDim.x * 256) {
    int s, d;
    load_edge(eb, E, w64, e, s, d);
    int pos = atomicAdd(&cursor[d], 1);
    int2 ent;
    ent.x = s;
    ent.y = __float_as_int(dinv[s] * dinv[d]);
    csr[rp[d] + pos] = ent;
  }
}

// ============================ W prep: transpose + fp16 (single launch) ============
// Wt[nc][k] = (f16) W[k][nc]; Wt3 zero-padded to 64 rows.
__global__ void prep_all(const float* __restrict__ W1, const float* __restrict__ W2,
                         const float* __restrict__ W3, f16* __restrict__ Wt1,
                         f16* __restrict__ Wt2, f16* __restrict__ Wt3) {
  int b = blockIdx.x, k = threadIdx.x;  // 128 threads
  if (b < 128) {
    Wt1[(size_t)b * 128 + k] = (f16)W1[(size_t)k * 128 + b];
  } else if (b < 256) {
    int nc = b - 128;
    Wt2[(size_t)nc * 128 + k] = (f16)W2[(size_t)k * 128 + nc];
  } else {
    int nc = b - 256;  // 0..63
    Wt3[(size_t)nc * 128 + k] = (nc < 40) ? (f16)W3[(size_t)k * 40 + nc] : (f16)0.f;
  }
}

// ============================ GEMM (MFMA f16) ============================
// H[n][NC] = act(X)[n][128] @ W[128][NC]; act = BN scale/shift + ReLU if BN.
// Block: 256 thr = 4 waves, tile 128 rows. Operand swap: mfma(Wfrag, Xfrag)
// puts 4 consecutive H-columns in each lane -> vectorized f16x4 stores.
template <int NCP, bool BN, bool F32IN>
__global__ __launch_bounds__(256) void gemm_mfma(const void* __restrict__ Xv,
                                                 const f16* __restrict__ Wt,
                                                 const float* __restrict__ ab,
                                                 f16* __restrict__ H, int n) {
  constexpr int CB = NCP / 16;
  __shared__ f16 Xs[128][136];
  __shared__ f16 Ws[NCP][136];
  const int t = threadIdx.x;
  const int m0 = blockIdx.x * 128;

  // ---- stage X tile (fp32 or fp16 global -> fp16 LDS, BN+ReLU fused) ----
  if constexpr (F32IN) {
    const float* X = (const float*)Xv;
#pragma unroll
    for (int p = 0; p < 16; p++) {
      int idx = p * 256 + t;          // 4096 float4 units
      int row = idx >> 5, c = (idx & 31) * 4;
      float4 v = make_float4(0.f, 0.f, 0.f, 0.f);
      if (m0 + row < n) v = *(const float4*)&X[(size_t)(m0 + row) * 128 + c];
      if (BN) {
        v.x = fmaxf(fmaf(v.x, ab[c + 0], ab[128 + c + 0]), 0.f);
        v.y = fmaxf(fmaf(v.y, ab[c + 1], ab[128 + c + 1]), 0.f);
        v.z = fmaxf(fmaf(v.z, ab[c + 2], ab[128 + c + 2]), 0.f);
        v.w = fmaxf(fmaf(v.w, ab[c + 3], ab[128 + c + 3]), 0.f);
      }
      f16x4 h = {(f16)v.x, (f16)v.y, (f16)v.z, (f16)v.w};
      *(f16x4*)&Xs[row][c] = h;
    }
  } else {
    const f16* X = (const f16*)Xv;
#pragma unroll
    for (int p = 0; p < 8; p++) {
      int idx = p * 256 + t;          // 2048 f16x8 units
      int row = idx >> 4, c = (idx & 15) * 8;
      f16x8 v = {0, 0, 0, 0, 0, 0, 0, 0};
      if (m0 + row < n) v = *(const f16x8*)&X[(size_t)(m0 + row) * 128 + c];
      if (BN) {
#pragma unroll
        for (int j = 0; j < 8; j++) {
          float f = (float)v[j];
          f = fmaxf(fmaf(f, ab[c + j], ab[128 + c + j]), 0.f);
          v[j] = (f16)f;
        }
      }
      *(f16x8*)&Xs[row][c] = v;
    }
  }
  // ---- stage W tile (fp16 global, pre-padded) ----
#pragma unroll
  for (int idx = t; idx < NCP * 16; idx += 256) {
    int row = idx >> 4, c = (idx & 15) * 8;
    *(f16x8*)&Ws[row][c] = *(const f16x8*)&Wt[(size_t)row * 128 + c];
  }
  __syncthreads();

  const int w = t >> 6, l = t & 63;
  const int lr = l & 15, lq = l >> 4;
  f32x4 acc[2][CB];
#pragma unroll
  for (int i = 0; i < 2; i++)
#pragma unroll
    for (int j = 0; j < CB; j++) acc[i][j] = (f32x4){0.f, 0.f, 0.f, 0.f};

#pragma unroll
  for (int kb = 0; kb < 4; kb++) {
    f16x8 xf0 = *(const f16x8*)&Xs[w * 32 + lr][kb * 32 + lq * 8];
    f16x8 xf1 = *(const f16x8*)&Xs[w * 32 + 16 + lr][kb * 32 + lq * 8];
#pragma unroll
    for (int cb = 0; cb < CB; cb++) {
      f16x8 wf = *(const f16x8*)&Ws[cb * 16 + lr][kb * 32 + lq * 8];
      acc[0][cb] = __builtin_amdgcn_mfma_f32_16x16x32_f16(wf, xf0, acc[0][cb], 0, 0, 0);
      acc[1][cb] = __builtin_amdgcn_mfma_f32_16x16x32_f16(wf, xf1, acc[1][cb], 0, 0, 0);
    }
  }
  // ---- store: lane holds H[row = base + (l&15)][col = cb*16 + lq*4 .. +3] ----
#pragma unroll
  for (int rg = 0; rg < 2; rg++) {
    int row = m0 + w * 32 + rg * 16 + lr;
    if (row >= n) continue;
#pragma unroll
    for (int cb = 0; cb < CB; cb++) {
      int col = cb * 16 + lq * 4;
      f32x4 a = acc[rg][cb];
      f16x4 h = {(f16)a[0], (f16)a[1], (f16)a[2], (f16)a[3]};
      *(f16x4*)&H[(size_t)row * NCP + col] = h;
    }
  }
}

// ============================ aggregation (gather, fp16 rows) ============================
// out[i][:] = bias + dinv[i]^2 * H[i][:] + sum_e norm[e] * H[src[e]][:]
// Grid-stride over nodes, one wave per node, edge loop unrolled x4 for MLP.
__global__ __launch_bounds__(256) void agg128h(const f16* __restrict__ H,
                                               const int* __restrict__ rp,
                                               const int2* __restrict__ csr,
                                               const float* __restrict__ dinv,
                                               const float* __restrict__ bias,
                                               f16* __restrict__ out, int n) {
  const int l = threadIdx.x & 63;
  const int gw = (blockIdx.x * 256 + threadIdx.x) >> 6;
  const int nw = (gridDim.x * 256) >> 6;
  const float2 bs = *(const float2*)&bias[l * 2];
  for (int i = gw; i < n; i += nw) {
    float di = dinv[i];
    float dii = di * di;
    float2 hf = __half22float2(*(const __half2*)&H[(size_t)i * 128 + l * 2]);
    float2 acc;
    acc.x = fmaf(hf.x, dii, bs.x);
    acc.y = fmaf(hf.y, dii, bs.y);
    int e = rp[i], e1 = rp[i + 1];
    for (; e + 4 <= e1; e += 4) {
      int2 c0 = csr[e], c1 = csr[e + 1], c2 = csr[e + 2], c3 = csr[e + 3];
      float2 v0 = __half22float2(*(const __half2*)&H[(size_t)c0.x * 128 + l * 2]);
      float2 v1 = __half22float2(*(const __half2*)&H[(size_t)c1.x * 128 + l * 2]);
      float2 v2 = __half22float2(*(const __half2*)&H[(size_t)c2.x * 128 + l * 2]);
      float2 v3 = __half22float2(*(const __half2*)&H[(size_t)c3.x * 128 + l * 2]);
      float w0 = __int_as_float(c0.y), w1 = __int_as_float(c1.y);
      float w2 = __int_as_float(c2.y), w3 = __int_as_float(c3.y);
      acc.x = fmaf(v0.x, w0, acc.x); acc.y = fmaf(v0.y, w0, acc.y);
      acc.x = fmaf(v1.x, w1, acc.x); acc.y = fmaf(v1.y, w1, acc.y);
      acc.x = fmaf(v2.x, w2, acc.x); acc.y = fmaf(v2.y, w2, acc.y);
      acc.x = fmaf(v3.x, w3, acc.x); acc.y = fmaf(v3.y, w3, acc.y);
    }
    for (; e < e1; e++) {
      int2 c0 = csr[e];
      float2 v0 = __half22float2(*(const __half2*)&H[(size_t)c0.x * 128 + l * 2]);
      float w0 = __int_as_float(c0.y);
      acc.x = fmaf(v0.x, w0, acc.x);
      acc.y = fmaf(v0.y, w0, acc.y);
    }
    *(__half2*)&out[(size_t)i * 128 + l * 2] = __floats2half2_rn(acc.x, acc.y);
  }
}

// layer-3: H padded to 64 cols (128B line-aligned rows), store only first 40.
__global__ __launch_bounds__(256) void agg64h(const f16* __restrict__ H,
                                              const int* __restrict__ rp,
                                              const int2* __restrict__ csr,
                                              const float* __restrict__ dinv,
                                              const float* __restrict__ bias,
                                              float* __restrict__ out, int n) {
  const int l = threadIdx.x & 63;
  const int gw = (blockIdx.x * 256 + threadIdx.x) >> 6;
  const int nw = (gridDim.x * 256) >> 6;
  const float bs = (l < 40) ? bias[l] : 0.f;
  for (int i = gw; i < n; i += nw) {
    float di = dinv[i];
    float acc = fmaf((float)H[(size_t)i * 64 + l], di * di, bs);
    int e = rp[i], e1 = rp[i + 1];
    for (; e + 4 <= e1; e += 4) {
      int2 c0 = csr[e], c1 = csr[e + 1], c2 = csr[e + 2], c3 = csr[e + 3];
      float v0 = (float)H[(size_t)c0.x * 64 + l];
      float v1 = (float)H[(size_t)c1.x * 64 + l];
      float v2 = (float)H[(size_t)c2.x * 64 + l];
      float v3 = (float)H[(size_t)c3.x * 64 + l];
      acc = fmaf(v0, __int_as_float(c0.y), acc);
      acc = fmaf(v1, __int_as_float(c1.y), acc);
      acc = fmaf(v2, __int_as_float(c2.y), acc);
      acc = fmaf(v3, __int_as_float(c3.y), acc);
    }
    for (; e < e1; e++) {
      int2 c0 = csr[e];
      acc = fmaf((float)H[(size_t)c0.x * 64 + l], __int_as_float(c0.y), acc);
    }
    if (l < 40) out[(size_t)i * 40 + l] = acc;
  }
}

// ============================ batchnorm stats (fp16 input) ============================
__global__ __launch_bounds__(256) void bn_stats_h(const f16* __restrict__ H, int n,
                                                  float* __restrict__ acc) {
  int t = threadIdx.x;
  int c2 = t & 63;   // half2 column
  int rg = t >> 6;   // 0..3
  float2 s = {0.f, 0.f}, s2 = {0.f, 0.f};
  for (int r = blockIdx.x * 4 + rg; r < n; r += gridDim.x * 4) {
    float2 v = __half22float2(*(const __half2*)&H[(size_t)r * 128 + c2 * 2]);
    s.x += v.x;
    s.y += v.y;
    s2.x = fmaf(v.x, v.x, s2.x);
    s2.y = fmaf(v.y, v.y, s2.y);
  }
  __shared__ float ls[4][128], ls2[4][128];
  ls[rg][c2 * 2] = s.x;
  ls[rg][c2 * 2 + 1] = s.y;
  ls2[rg][c2 * 2] = s2.x;
  ls2[rg][c2 * 2 + 1] = s2.y;
  __syncthreads();
  if (t < 128) {
    float a_ = ls[0][t] + ls[1][t] + ls[2][t] + ls[3][t];
    float b_ = ls2[0][t] + ls2[1][t] + ls2[2][t] + ls2[3][t];
    atomicAdd(&acc[t], a_);
    atomicAdd(&acc[128 + t], b_);
  }
}

__global__ void bn_final(const float* __restrict__ acc, const float* __restrict__ g,
                         const float* __restrict__ bt, int n,
                         float* __restrict__ ab) {
  int c = threadIdx.x;  // 128
  float inv_n = 1.0f / (float)n;
  float mean = acc[c] * inv_n;
  float var = acc[128 + c] * inv_n - mean * mean;
  float sc = g[c] * rsqrtf(var + BN_EPS);
  ab[c] = sc;
  ab[128 + c] = fmaf(-mean, sc, bt[c]);
}

// ============================ launch ============================
extern "C" void kernel_launch(void* const* d_in, const int* in_sizes, int n_in,
                              void* d_out, int out_size, void* d_ws, size_t ws_size,
                              hipStream_t stream) {
  const float* x = (const float*)d_in[0];
  const void* eb = d_in[1];
  const float* W1 = (const float*)d_in[2];
  const float* b1 = (const float*)d_in[3];
  const float* g1 = (const float*)d_in[4];
  const float* bt1 = (const float*)d_in[5];
  const float* W2 = (const float*)d_in[6];
  const float* b2 = (const float*)d_in[7];
  const float* g2 = (const float*)d_in[8];
  const float* bt2 = (const float*)d_in[9];
  const float* W3 = (const float*)d_in[10];
  const float* b3 = (const float*)d_in[11];

  const int n = in_sizes[0] / 128;
  const int E = in_sizes[1] / 2;

  char* w = (char*)d_ws;
  auto alloc = [&](size_t bytes) {
    void* p = (void*)w;
    w += (bytes + 255) & ~(size_t)255;
    return p;
  };
  f16* hA = (f16*)alloc((size_t)n * 128 * 2);
  f16* hB = (f16*)alloc((size_t)n * 128 * 2);
  int2* csr = (int2*)alloc((size_t)E * 8);
  float* dinv = (float*)alloc((size_t)n * 4);
  int* rp = (int*)alloc((size_t)(n + 1) * 4);
  int* bsum = (int*)alloc(512 * 4);
  int* boff = (int*)alloc(512 * 4);
  float* ab1 = (float*)alloc(256 * 4);
  float* ab2 = (float*)alloc(256 * 4);
  f16* Wt1 = (f16*)alloc(128 * 128 * 2);
  f16* Wt2 = (f16*)alloc(128 * 128 * 2);
  f16* Wt3 = (f16*)alloc(64 * 128 * 2);
  // contiguous zero region:
  int* counts = (int*)alloc((size_t)n * 4);
  int* cursor = (int*)alloc((size_t)n * 4);
  float* bn_acc1 = (float*)alloc(256 * 4);
  float* bn_acc2 = (float*)alloc(256 * 4);
  int* flag = (int*)alloc(256);
  size_t zbytes = (char*)flag + 256 - (char*)counts;
  hipMemsetAsync(counts, 0, zbytes, stream);

  const int NB = (n + 255) / 256;

  prep_all<<<320, 128, 0, stream>>>(W1, W2, W3, Wt1, Wt2, Wt3);

  detect_k<<<512, 256, 0, stream>>>((const unsigned*)eb, E, flag);
  count_k<<<2048, 256, 0, stream>>>(eb, E, flag, counts);
  scan1_k<<<NB, 256, 0, stream>>>(counts, bsum, dinv, n);
  scan2_k<<<1, 512, 0, stream>>>(bsum, boff, NB);
  scan3_k<<<NB, 256, 0, stream>>>(counts, boff, rp, n, E);
  fill_k<<<2048, 256, 0, stream>>>(eb, E, flag, rp, cursor, dinv, csr);

  const int GB = (n + 127) / 128;  // gemm blocks
  const int AGB = 4096;            // agg blocks (grid-stride, 16K waves)

  // layer 1
  gemm_mfma<128, false, true><<<GB, 256, 0, stream>>>(x, Wt1, nullptr, hA, n);
  agg128h<<<AGB, 256, 0, stream>>>(hA, rp, csr, dinv, b1, hB, n);
  bn_stats_h<<<1024, 256, 0, stream>>>(hB, n, bn_acc1);
  bn_final<<<1, 128, 0, stream>>>(bn_acc1, g1, bt1, n, ab1);
  // layer 2
  gemm_mfma<128, true, false><<<GB, 256, 0, stream>>>(hB, Wt2, ab1, hA, n);
  agg128h<<<AGB, 256, 0, stream>>>(hA, rp, csr, dinv, b2, hB, n);
  bn_stats_h<<<1024, 256, 0, stream>>>(hB, n, bn_acc2);
  bn_final<<<1, 128, 0, stream>>>(bn_acc2, g2, bt2, n, ab2);
  // layer 3 (H padded to 64 cols for line-aligned gathers)
  gemm_mfma<64, true, false><<<GB, 256, 0, stream>>>(hB, Wt3, ab2, hA, n);
  agg64h<<<AGB, 256, 0, stream>>>(hA, rp, csr, dinv, b3, (float*)d_out, n);
}